// Round 9
// baseline (175.654 us; speedup 1.0000x reference)
//
#include <hip/hip_runtime.h>
#include <stdint.h>

// Problem constants
#define BB 2
#define SS 2048
#define HH 1024
#define NH 16
#define HD 64

#define LOG2E 1.4426950408889634f
#define QSCALE (0.125f * LOG2E)   // folded into Q at GEMM epilogue

typedef short bfrag  __attribute__((ext_vector_type(8)));   // 8 x bf16 (4 VGPRs)
typedef short bfrag4 __attribute__((ext_vector_type(4)));   // 4 x bf16 (2 VGPRs)
typedef float f32x4  __attribute__((ext_vector_type(4)));

__device__ __forceinline__ short f2bf(float f) {
    union { float f; uint32_t u; } v; v.f = f;
    uint32_t r = (v.u + 0x7fffu + ((v.u >> 16) & 1u)) >> 16;
    return (short)r;
}

// fused fp32->bf16 conversion: hidden (1048576 f4) + Wq/Wk/Wv (262144 f4 each,
// into contiguous Wcat) + mask*LOG2E (1024 f4, fp32 out). grid 7172.
__global__ __launch_bounds__(256) void cvt_all(
    const float* __restrict__ X,  const float* __restrict__ Wq,
    const float* __restrict__ Wk, const float* __restrict__ Wv,
    const float* __restrict__ mask,
    short* __restrict__ Xb, short* __restrict__ Wcat,
    float* __restrict__ maskl)
{
    int i = blockIdx.x * 256 + threadIdx.x;
    if (i >= 1835008) {
        int off = i - 1835008;   // 0..1023
        float4 f = ((const float4*)mask)[off];
        f.x *= LOG2E; f.y *= LOG2E; f.z *= LOG2E; f.w *= LOG2E;
        ((float4*)maskl)[off] = f;
        return;
    }
    const float* src; short* dst; int off;
    if (i < 1048576)      { src = X;  dst = Xb;                 off = i; }
    else if (i < 1310720) { src = Wq; dst = Wcat;               off = i - 1048576; }
    else if (i < 1572864) { src = Wk; dst = Wcat + 1048576;     off = i - 1310720; }
    else                  { src = Wv; dst = Wcat + 2097152;     off = i - 1572864; }
    float4 f = ((const float4*)src)[off];
    short4 s;
    s.x = f2bf(f.x); s.y = f2bf(f.y); s.z = f2bf(f.z); s.w = f2bf(f.w);
    ((short4*)dst)[off] = s;
}

__device__ __forceinline__ void gload_lds16(const void* g, void* lds) {
    __builtin_amdgcn_global_load_lds(
        (__attribute__((address_space(1))) void*)(uintptr_t)g,
        (__attribute__((address_space(3))) void*)(uintptr_t)lds,
        16, 0, 0);
}

// Fused QKV GEMM: C[m][n] = sum_k X[m][k] * Wcat[n][k] + bias, M=4096 N=3072 K=1024.
// n in [0,1024) -> Q (pre-scaled by QSCALE), [1024,2048) -> K, [2048,3072) -> V^T.
// ONE-barrier K-loop: BK=32, LDS double-buffer (2 x 16KB), global_load_lds DMA for
// tile j+1 issued right after the barrier -> the vmcnt drain waits on loads that
// aged a full compute phase (X/W panels are L2-resident from cross-block reuse).
__global__ __launch_bounds__(256, 3) void qkv_gemm(
    const short* __restrict__ X, const short* __restrict__ Wcat,
    const float* __restrict__ bq, const float* __restrict__ bk, const float* __restrict__ bv,
    short* __restrict__ Qo, short* __restrict__ Ko, short* __restrict__ Vo)
{
    // stages: A0@0, B0@8192, A1@16384, B1@24576 (bytes). epilogue reuses as T[128][136].
    __shared__ __align__(16) short smem[17408];

    const int tid  = threadIdx.x;
    const int wave = tid >> 6, lane = tid & 63;
    const int quad = lane >> 4, l15 = lane & 15;
    const int mTile = blockIdx.y * 128;
    const int nTile = blockIdx.x * 128;
    const int z = nTile >> 10;                 // 0=Q,1=K,2=V (block-uniform)
    const int nLocT = nTile & 1023;
    const float* bias = (z == 0) ? bq : (z == 1) ? bk : bv;

    f32x4 acc[4][4];
#pragma unroll
    for (int i = 0; i < 4; ++i)
#pragma unroll
        for (int j = 0; j < 4; ++j) acc[i][j] = (f32x4)0.0f;

    const int mBase = (wave >> 1) * 64;
    const int nBase = (wave & 1) * 64;

    // staging: tile = 128 rows x 32 shorts (64B rows) = 8KB = 512 chunks of 16B.
    // wave w instr i covers chunks (i*4+w)*64 + lane; r=ci>>2, c=ci&3;
    // LDS slot c holds global chunk c^(r&3) (source-side swizzle).
    int asrc[2];
#pragma unroll
    for (int i = 0; i < 2; ++i) {
        int ci = (i * 4 + wave) * 64 + lane;
        int r = ci >> 2, c = ci & 3;
        asrc[i] = r * 2048 + ((c ^ (r & 3)) * 16);
    }
    const int dmaDst0 = wave * 1024;           // instr i adds (i*4)*1024
    const char* aBase = (const char*)X + (size_t)mTile * 2048;
    const char* bBase = (const char*)Wcat + (size_t)nTile * 2048;

    // fragment read offsets within a stage: row = mBase + t*16 + l15,
    // addr = row*64 + (quad ^ (l15&3))*16  (+ t*1024)
    const int aAddr = (mBase + l15) * 64 + ((quad ^ (l15 & 3)) * 16);
    const int bAddr = (nBase + l15) * 64 + ((quad ^ (l15 & 3)) * 16);

    // prologue: tile 0 -> stage 0
#pragma unroll
    for (int i = 0; i < 2; ++i) {
        gload_lds16(aBase + asrc[i], (char*)smem + dmaDst0 + i * 4096);
        gload_lds16(bBase + asrc[i], (char*)smem + 8192 + dmaDst0 + i * 4096);
    }

    auto qstep = [&](int CUR, int NXT, int koffN, int pref) {
        __syncthreads();   // tile-j DMA landed; prior compute done (other buffer free)
        if (pref) {
#pragma unroll
            for (int i = 0; i < 2; ++i) {
                gload_lds16(aBase + koffN + asrc[i], (char*)smem + NXT + dmaDst0 + i * 4096);
                gload_lds16(bBase + koffN + asrc[i], (char*)smem + NXT + 8192 + dmaDst0 + i * 4096);
            }
        }
        bfrag af[4], bf[4];
#pragma unroll
        for (int t = 0; t < 4; ++t) {
            af[t] = *(const bfrag*)((const char*)smem + CUR + aAddr + t * 1024);
            bf[t] = *(const bfrag*)((const char*)smem + CUR + 8192 + bAddr + t * 1024);
        }
#pragma unroll
        for (int mt = 0; mt < 4; ++mt)
#pragma unroll
            for (int ct = 0; ct < 4; ++ct)
                acc[mt][ct] = __builtin_amdgcn_mfma_f32_16x16x32_bf16(
                    af[mt], bf[ct], acc[mt][ct], 0, 0, 0);
    };

    for (int kk = 0; kk < 16; ++kk) {
        qstep(0,     16384, (2 * kk + 1) * 64, 1);
        qstep(16384, 0,     (2 * kk + 2) * 64, kk < 15);
    }

    __syncthreads();   // main-loop LDS reads complete before T overwrite
    const int b = mTile >> 11, sBase = mTile & 2047;

    if (z == 2) {
        // T[n-local][s-local], pitch 136 -> coalesced V^T [bh][d][s] stores
#pragma unroll
        for (int mt = 0; mt < 4; ++mt)
#pragma unroll
            for (int ct = 0; ct < 4; ++ct)
#pragma unroll
                for (int r = 0; r < 4; ++r) {
                    int nl = nBase + ct * 16 + l15;
                    int sl = mBase + mt * 16 + quad * 4 + r;
                    smem[nl * 136 + sl] = f2bf(acc[mt][ct][r] + bias[nLocT + nl]);
                }
        __syncthreads();
#pragma unroll
        for (int p = 0; p < 8; ++p) {
            int nl = p * 16 + (tid >> 4);
            int c  = tid & 15;
            bfrag v8 = *(const bfrag*)(smem + nl * 136 + c * 8);
            int ng = nLocT + nl, hh = ng >> 6, d = ng & 63;
            *(bfrag*)(Vo + ((size_t)(b * 16 + hh) * 64 + d) * 2048 + sBase + c * 8) = v8;
        }
    } else {
        short* Out = (z == 0) ? Qo : Ko;
        float scale = (z == 0) ? QSCALE : 1.0f;
        // T[s-local][n-local], pitch 136 -> coalesced [bh][s][d] stores
#pragma unroll
        for (int mt = 0; mt < 4; ++mt)
#pragma unroll
            for (int ct = 0; ct < 4; ++ct)
#pragma unroll
                for (int r = 0; r < 4; ++r) {
                    int ml = mBase + mt * 16 + quad * 4 + r;
                    int nl = nBase + ct * 16 + l15;
                    smem[ml * 136 + nl] = f2bf((acc[mt][ct][r] + bias[nLocT + nl]) * scale);
                }
        __syncthreads();
#pragma unroll
        for (int p = 0; p < 8; ++p) {
            int ml = p * 16 + (tid >> 4);
            int c  = tid & 15;
            bfrag v8 = *(const bfrag*)(smem + ml * 136 + c * 8);
            int s  = sBase + ml;
            int nl = nLocT + c * 8, hh = nl >> 6, d = nl & 63;
            *(bfrag*)(Out + (((size_t)(b * 16 + hh) << 11) + s) * 64 + d) = v8;
        }
    }
}

// Flash attention (no-max softmax, log2 domain; Q pre-scaled by 0.125*log2e).
// One block = 64 Q rows of one (b,h); 4 waves x 16 rows. Grid 1024.
// Bc=64; LDS double-buffer with DMA staging, ONE barrier/iter, manually unrolled
// by 2 so both stages are addressed with constant offsets (no per-iter base adds).
// exp2 via __builtin_amdgcn_exp2f (single v_exp_f32).
__global__ __launch_bounds__(256, 4) void attn_kernel(
    const short* __restrict__ Qb, const short* __restrict__ Kb, const short* __restrict__ Vb,
    const float* __restrict__ maskl, float* __restrict__ out)
{
    __shared__ __align__(16) char smem[32768];
    // stage = 16384 B: K tile [64][64] bf16 @+0 (128B rows, XOR-swizzled 16B chunks),
    //                  V^T tile [64][64] bf16 @+8192 (same layout)

    const int tid  = threadIdx.x;
    const int wave = tid >> 6, lane = tid & 63;
    const int quad = lane >> 4, l15 = lane & 15;
    const int bh = blockIdx.y, b = bh >> 4, h = bh & 15;
    const int qBase = blockIdx.x * 64 + wave * 16;

    // staging source byte offsets (wave handles chunks wave*128 + i*64 + lane)
    int ksrc[2], vsrc[2];
#pragma unroll
    for (int i = 0; i < 2; ++i) {
        int ci = wave * 128 + i * 64 + lane;
        int r = ci >> 3, c = ci & 7;
        int cs = (c ^ (r & 7)) * 16;
        ksrc[i] = r * 128  + cs;    // K source: row stride 64 shorts = 128B
        vsrc[i] = r * 4096 + cs;    // V^T source: row stride 2048 shorts = 4096B
    }
    const char* kBase = (const char*)(Kb + (size_t)bh * SS * HD);
    const char* vBase = (const char*)(Vb + (size_t)bh * HD * SS);
    const char* mSrc  = (const char*)(maskl + b * SS) + quad * 16;

    // Q fragment (MFMA B-operand): Q[qrow=l15][k=quad*8+j], pre-scaled
    const short* Qp = Qb + ((size_t)bh * SS + qBase) * HD;
    bfrag qf[2];
#pragma unroll
    for (int kt = 0; kt < 2; ++kt)
        qf[kt] = *(const bfrag*)(Qp + (size_t)l15 * HD + kt * 32 + quad * 8);

    // j-invariant LDS read offsets (within a stage)
    int kAddr[2];
#pragma unroll
    for (int kt = 0; kt < 2; ++kt)
        kAddr[kt] = l15 * 128 + (((kt * 4 + quad) ^ (l15 & 7)) * 16);
    int vAddr[4];
#pragma unroll
    for (int ct = 0; ct < 4; ++ct)
        vAddr[ct] = 8192 + l15 * 128 + (((ct * 2 + (quad >> 1)) ^ (l15 & 7)) * 16) + (quad & 1) * 8;

    const f32x4 z4 = (f32x4)0.0f;
    const bfrag4 ones = {0x3F80, 0x3F80, 0x3F80, 0x3F80};  // bf16 1.0 x4

    f32x4 oacc[4], ol = z4;
#pragma unroll
    for (int dt = 0; dt < 4; ++dt) oacc[dt] = z4;

    // prologue: stage tile 0 into buffer 0
#pragma unroll
    for (int i = 0; i < 2; ++i) {
        gload_lds16(kBase + ksrc[i], smem + wave * 2048 + i * 1024);
        gload_lds16(vBase + vsrc[i], smem + 8192 + wave * 2048 + i * 1024);
    }

    auto astep = [&](int CUR, int NXT, int jn, int pref) {
        __syncthreads();   // tile-j loads landed; prior compute done (buffer free)
        if (pref) {
#pragma unroll
            for (int i = 0; i < 2; ++i) {
                gload_lds16(kBase + jn * 8192 + ksrc[i], smem + NXT + wave * 2048 + i * 1024);
                gload_lds16(vBase + jn * 128  + vsrc[i], smem + NXT + 8192 + wave * 2048 + i * 1024);
            }
        }

        // mask (pre-multiplied by log2e)
        f32x4 mvl[4];
#pragma unroll
        for (int ct = 0; ct < 4; ++ct)
            mvl[ct] = *(const f32x4*)(mSrc + ct * 64);
        mSrc += 256;

        // S^T = K * Q^T : s[ct] holds C[kcol=ct*16+quad*4+r][qrow=l15]
        f32x4 s[4];
#pragma unroll
        for (int ct = 0; ct < 4; ++ct) {
            bfrag kf0 = *(const bfrag*)(smem + CUR + kAddr[0] + ct * 2048);
            bfrag kf1 = *(const bfrag*)(smem + CUR + kAddr[1] + ct * 2048);
            s[ct] = __builtin_amdgcn_mfma_f32_16x16x32_bf16(kf0, qf[0], z4,    0, 0, 0);
            s[ct] = __builtin_amdgcn_mfma_f32_16x16x32_bf16(kf1, qf[1], s[ct], 0, 0, 0);
        }

        // softmax numerators (no max subtraction; scores O(1) by construction)
        bfrag4 pf[4];
#pragma unroll
        for (int ct = 0; ct < 4; ++ct) {
            uint32_t a0 = __float_as_uint(__builtin_amdgcn_exp2f(s[ct][0] + mvl[ct][0])) + 0x8000u;
            uint32_t a1 = __float_as_uint(__builtin_amdgcn_exp2f(s[ct][1] + mvl[ct][1])) + 0x8000u;
            uint32_t a2 = __float_as_uint(__builtin_amdgcn_exp2f(s[ct][2] + mvl[ct][2])) + 0x8000u;
            uint32_t a3 = __float_as_uint(__builtin_amdgcn_exp2f(s[ct][3] + mvl[ct][3])) + 0x8000u;
            union { uint32_t u[2]; bfrag4 v; } cvt;
            cvt.u[0] = __builtin_amdgcn_perm(a1, a0, 0x07060302u);
            cvt.u[1] = __builtin_amdgcn_perm(a3, a2, 0x07060302u);
            pf[ct] = cvt.v;
        }

        // O += P*V ; l += P*ones
#pragma unroll
        for (int dt = 0; dt < 4; ++dt) {
#pragma unroll
            for (int ct = 0; ct < 4; ++ct) {
                bfrag4 vf = *(const bfrag4*)(smem + CUR + vAddr[ct] + dt * 2048);
                oacc[dt] = __builtin_amdgcn_mfma_f32_16x16x16bf16_1k(pf[ct], vf, oacc[dt], 0, 0, 0);
            }
        }
#pragma unroll
        for (int ct = 0; ct < 4; ++ct)
            ol = __builtin_amdgcn_mfma_f32_16x16x16bf16_1k(pf[ct], ones, ol, 0, 0, 0);
    };

    for (int jj = 0; jj < 16; ++jj) {
        astep(0,     16384, 2 * jj + 1, 1);
        astep(16384, 0,     2 * jj + 2, jj < 15);
    }

    // epilogue: out[b][qrow][h*64+d] fp32; O rows = quad*4+r, cols = l15 (+16*dt)
#pragma unroll
    for (int r = 0; r < 4; ++r) {
        float linv = 1.0f / ol[r];
        int qrow = qBase + quad * 4 + r;
#pragma unroll
        for (int dt = 0; dt < 4; ++dt)
            out[((size_t)(b * SS + qrow)) * HH + h * 64 + dt * 16 + l15] =
                oacc[dt][r] * linv;
    }
}

extern "C" void kernel_launch(void* const* d_in, const int* in_sizes, int n_in,
                              void* d_out, int out_size, void* d_ws, size_t ws_size,
                              hipStream_t stream) {
    const float* hs   = (const float*)d_in[0];
    const float* mask = (const float*)d_in[1];
    const float* Wq   = (const float*)d_in[2];
    const float* bq   = (const float*)d_in[3];
    const float* Wk   = (const float*)d_in[4];
    const float* bk   = (const float*)d_in[5];
    const float* Wv   = (const float*)d_in[6];
    const float* bv   = (const float*)d_in[7];
    float* out = (float*)d_out;

    char* ws = (char*)d_ws;
    short* Xb    = (short*)(ws);                      // [4096][1024] bf16, 8 MiB
    short* Wcat  = (short*)(ws + (8ull  << 20));      // [3072][1024] bf16, 6 MiB (Wq|Wk|Wv)
    short* Qb    = (short*)(ws + (14ull << 20));      // [bh][s][d] 8 MiB (pre-scaled)
    short* Kb    = (short*)(ws + (22ull << 20));      // [bh][s][d] 8 MiB
    short* Vb    = (short*)(ws + (30ull << 20));      // [bh][d][s] 8 MiB
    float* maskl = (float*)(ws + (38ull << 20));      // [B][S] fp32, 16 KiB

    cvt_all<<<7172, 256, 0, stream>>>(hs, Wq, Wk, Wv, mask, Xb, Wcat, maskl);

    qkv_gemm<<<dim3(24, 32), 256, 0, stream>>>(Xb, Wcat, bq, bk, bv, Qb, Kb, Vb);

    attn_kernel<<<dim3(SS / 64, BB * NH), 256, 0, stream>>>(Qb, Kb, Vb, maskl, out);
}

// Round 10
// 174.148 us; speedup vs baseline: 1.0086x; 1.0086x over previous
//
#include <hip/hip_runtime.h>
#include <stdint.h>

// Problem constants
#define BB 2
#define SS 2048
#define HH 1024
#define NH 16
#define HD 64

#define LOG2E 1.4426950408889634f
#define QSCALE (0.125f * LOG2E)   // folded into Q at GEMM epilogue

typedef short bfrag  __attribute__((ext_vector_type(8)));   // 8 x bf16 (4 VGPRs)
typedef short bfrag4 __attribute__((ext_vector_type(4)));   // 4 x bf16 (2 VGPRs)
typedef float f32x4  __attribute__((ext_vector_type(4)));

__device__ __forceinline__ short f2bf(float f) {
    union { float f; uint32_t u; } v; v.f = f;
    uint32_t r = (v.u + 0x7fffu + ((v.u >> 16) & 1u)) >> 16;
    return (short)r;
}

// pack two f32 -> one dword of bf16 (lo = a, hi = b)
__device__ __forceinline__ uint32_t pack_bf16(float a, float b) {
#if __has_builtin(__builtin_amdgcn_cvt_pk_bf16_f32)
    auto t = __builtin_amdgcn_cvt_pk_bf16_f32(a, b);   // RNE, single VALU op
    uint32_t u; __builtin_memcpy(&u, &t, 4);
    return u;
#else
    uint32_t ua = __float_as_uint(a) + 0x8000u;
    uint32_t ub = __float_as_uint(b) + 0x8000u;
    return __builtin_amdgcn_perm(ub, ua, 0x07060302u);
#endif
}

// fused fp32->bf16 conversion: hidden (1048576 f4) + Wq/Wk/Wv (262144 f4 each,
// into contiguous Wcat) + mask*LOG2E (1024 f4, fp32 out). grid 7172.
__global__ __launch_bounds__(256) void cvt_all(
    const float* __restrict__ X,  const float* __restrict__ Wq,
    const float* __restrict__ Wk, const float* __restrict__ Wv,
    const float* __restrict__ mask,
    short* __restrict__ Xb, short* __restrict__ Wcat,
    float* __restrict__ maskl)
{
    int i = blockIdx.x * 256 + threadIdx.x;
    if (i >= 1835008) {
        int off = i - 1835008;   // 0..1023
        float4 f = ((const float4*)mask)[off];
        f.x *= LOG2E; f.y *= LOG2E; f.z *= LOG2E; f.w *= LOG2E;
        ((float4*)maskl)[off] = f;
        return;
    }
    const float* src; short* dst; int off;
    if (i < 1048576)      { src = X;  dst = Xb;                 off = i; }
    else if (i < 1310720) { src = Wq; dst = Wcat;               off = i - 1048576; }
    else if (i < 1572864) { src = Wk; dst = Wcat + 1048576;     off = i - 1310720; }
    else                  { src = Wv; dst = Wcat + 2097152;     off = i - 1572864; }
    float4 f = ((const float4*)src)[off];
    short4 s;
    s.x = f2bf(f.x); s.y = f2bf(f.y); s.z = f2bf(f.z); s.w = f2bf(f.w);
    ((short4*)dst)[off] = s;
}

__device__ __forceinline__ void gload_lds16(const void* g, void* lds) {
    __builtin_amdgcn_global_load_lds(
        (__attribute__((address_space(1))) void*)(uintptr_t)g,
        (__attribute__((address_space(3))) void*)(uintptr_t)lds,
        16, 0, 0);
}

// Fused QKV GEMM (round-8 structure: BK=64, 2-barrier K-loop — BK=32 1-barrier
// variant regressed: halved MFMA-per-barrier worsened amortization, m132-style).
// C[m][n] = sum_k X[m][k] * Wcat[n][k] + bias, M=4096 N=3072 K=1024.
// n in [0,1024) -> Q (pre-scaled by QSCALE), [1024,2048) -> K, [2048,3072) -> V^T.
__global__ __launch_bounds__(256, 3) void qkv_gemm(
    const short* __restrict__ X, const short* __restrict__ Wcat,
    const float* __restrict__ bq, const float* __restrict__ bk, const float* __restrict__ bv,
    short* __restrict__ Qo, short* __restrict__ Ko, short* __restrict__ Vo)
{
    // main loop: As = smem[0..8191], Bs = smem[8192..16383] (shorts)
    // epilogue: reused as T[128][136] (17408 shorts)
    __shared__ __align__(16) short smem[17408];

    const int tid  = threadIdx.x;
    const int wave = tid >> 6, lane = tid & 63;
    const int quad = lane >> 4, l15 = lane & 15;
    const int mTile = blockIdx.y * 128;
    const int nTile = blockIdx.x * 128;
    const int z = nTile >> 10;                 // 0=Q,1=K,2=V (block-uniform)
    const int nLocT = nTile & 1023;
    const float* bias = (z == 0) ? bq : (z == 1) ? bk : bv;

    f32x4 acc[4][4];
#pragma unroll
    for (int i = 0; i < 4; ++i)
#pragma unroll
        for (int j = 0; j < 4; ++j) acc[i][j] = (f32x4)0.0f;

    const int srow  = lane >> 3;   // 0..7
    const int c_lin = lane & 7;
    const int mBase = (wave >> 1) * 64;
    const int nBase = (wave & 1) * 64;

    for (int k0 = 0; k0 < 1024; k0 += 64) {
        __syncthreads();
#pragma unroll
        for (int i = 0; i < 4; ++i) {
            int row = i * 32 + wave * 8 + srow;
            int cg  = c_lin ^ (row & 7);
            gload_lds16(X + (size_t)(mTile + row) * 1024 + k0 + cg * 8,
                        (char*)smem + i * 4096 + wave * 1024);
            gload_lds16(Wcat + (size_t)(nTile + row) * 1024 + k0 + cg * 8,
                        (char*)smem + 16384 + i * 4096 + wave * 1024);
        }
        __syncthreads();

#pragma unroll
        for (int kt = 0; kt < 2; ++kt) {
            bfrag af[4], bf[4];
#pragma unroll
            for (int t = 0; t < 4; ++t) {
                int arow = mBase + t * 16 + l15;
                int aslot = (kt * 4 + quad) ^ (arow & 7);
                af[t] = *(const bfrag*)((const char*)smem + arow * 128 + aslot * 16);
                int brow = nBase + t * 16 + l15;
                int bslot = (kt * 4 + quad) ^ (brow & 7);
                bf[t] = *(const bfrag*)((const char*)smem + 16384 + brow * 128 + bslot * 16);
            }
#pragma unroll
            for (int mt = 0; mt < 4; ++mt)
#pragma unroll
                for (int ct = 0; ct < 4; ++ct)
                    acc[mt][ct] = __builtin_amdgcn_mfma_f32_16x16x32_bf16(
                        af[mt], bf[ct], acc[mt][ct], 0, 0, 0);
        }
    }

    __syncthreads();   // main-loop LDS reads complete before T overwrite
    const int b = mTile >> 11, sBase = mTile & 2047;

    if (z == 2) {
        // T[n-local][s-local], pitch 136 -> coalesced V^T [bh][d][s] stores
#pragma unroll
        for (int mt = 0; mt < 4; ++mt)
#pragma unroll
            for (int ct = 0; ct < 4; ++ct)
#pragma unroll
                for (int r = 0; r < 4; ++r) {
                    int nl = nBase + ct * 16 + l15;
                    int sl = mBase + mt * 16 + quad * 4 + r;
                    smem[nl * 136 + sl] = f2bf(acc[mt][ct][r] + bias[nLocT + nl]);
                }
        __syncthreads();
#pragma unroll
        for (int p = 0; p < 8; ++p) {
            int nl = p * 16 + (tid >> 4);
            int c  = tid & 15;
            bfrag v8 = *(const bfrag*)(smem + nl * 136 + c * 8);
            int ng = nLocT + nl, hh = ng >> 6, d = ng & 63;
            *(bfrag*)(Vo + ((size_t)(b * 16 + hh) * 64 + d) * 2048 + sBase + c * 8) = v8;
        }
    } else {
        short* Out = (z == 0) ? Qo : Ko;
        float scale = (z == 0) ? QSCALE : 1.0f;
        // T[s-local][n-local], pitch 136 -> coalesced [bh][s][d] stores
#pragma unroll
        for (int mt = 0; mt < 4; ++mt)
#pragma unroll
            for (int ct = 0; ct < 4; ++ct)
#pragma unroll
                for (int r = 0; r < 4; ++r) {
                    int ml = mBase + mt * 16 + quad * 4 + r;
                    int nl = nBase + ct * 16 + l15;
                    smem[ml * 136 + nl] = f2bf((acc[mt][ct][r] + bias[nLocT + nl]) * scale);
                }
        __syncthreads();
#pragma unroll
        for (int p = 0; p < 8; ++p) {
            int ml = p * 16 + (tid >> 4);
            int c  = tid & 15;
            bfrag v8 = *(const bfrag*)(smem + ml * 136 + c * 8);
            int s  = sBase + ml;
            int nl = nLocT + c * 8, hh = nl >> 6, d = nl & 63;
            *(bfrag*)(Out + (((size_t)(b * 16 + hh) << 11) + s) * 64 + d) = v8;
        }
    }
}

// Flash attention (no-max softmax, log2 domain; Q pre-scaled by 0.125*log2e).
// One block = 64 Q rows of one (b,h); 4 waves x 16 rows. Grid 1024.
// Bc=64; LDS double-buffer with DMA staging, ONE barrier/iter.
// Softmax VALU minimized: mask folded into the QK MFMA C-operand (zero adds),
// P packed with v_cvt_pk_bf16_f32 (RNE, 1 op / 2 values).
__global__ __launch_bounds__(256, 4) void attn_kernel(
    const short* __restrict__ Qb, const short* __restrict__ Kb, const short* __restrict__ Vb,
    const float* __restrict__ maskl, float* __restrict__ out)
{
    __shared__ __align__(16) char smem[32768];
    // stage = 16384 B: K tile [64][64] bf16 @+0 (128B rows, XOR-swizzled 16B chunks),
    //                  V^T tile [64][64] bf16 @+8192 (same layout)

    const int tid  = threadIdx.x;
    const int wave = tid >> 6, lane = tid & 63;
    const int quad = lane >> 4, l15 = lane & 15;
    const int bh = blockIdx.y, b = bh >> 4, h = bh & 15;
    const int qBase = blockIdx.x * 64 + wave * 16;

    // staging source byte offsets (wave handles chunks wave*128 + i*64 + lane)
    int ksrc[2], vsrc[2];
#pragma unroll
    for (int i = 0; i < 2; ++i) {
        int ci = wave * 128 + i * 64 + lane;
        int r = ci >> 3, c = ci & 7;
        int cs = (c ^ (r & 7)) * 16;
        ksrc[i] = r * 128  + cs;    // K source: row stride 64 shorts = 128B
        vsrc[i] = r * 4096 + cs;    // V^T source: row stride 2048 shorts = 4096B
    }
    const char* kBase = (const char*)(Kb + (size_t)bh * SS * HD);
    const char* vBase = (const char*)(Vb + (size_t)bh * HD * SS);
    const char* mSrc  = (const char*)(maskl + b * SS) + quad * 16;

    // Q fragment (MFMA B-operand): Q[qrow=l15][k=quad*8+j], pre-scaled
    const short* Qp = Qb + ((size_t)bh * SS + qBase) * HD;
    bfrag qf[2];
#pragma unroll
    for (int kt = 0; kt < 2; ++kt)
        qf[kt] = *(const bfrag*)(Qp + (size_t)l15 * HD + kt * 32 + quad * 8);

    // j-invariant LDS read offsets (within a stage)
    int kAddr[2];
#pragma unroll
    for (int kt = 0; kt < 2; ++kt)
        kAddr[kt] = l15 * 128 + (((kt * 4 + quad) ^ (l15 & 7)) * 16);
    int vAddr[4];
#pragma unroll
    for (int ct = 0; ct < 4; ++ct)
        vAddr[ct] = 8192 + l15 * 128 + (((ct * 2 + (quad >> 1)) ^ (l15 & 7)) * 16) + (quad & 1) * 8;

    const f32x4 z4 = (f32x4)0.0f;
    const bfrag4 ones = {0x3F80, 0x3F80, 0x3F80, 0x3F80};  // bf16 1.0 x4

    f32x4 oacc[4], ol = z4;
#pragma unroll
    for (int dt = 0; dt < 4; ++dt) oacc[dt] = z4;

    // prologue: stage tile 0 into buffer 0
#pragma unroll
    for (int i = 0; i < 2; ++i) {
        gload_lds16(kBase + ksrc[i], smem + wave * 2048 + i * 1024);
        gload_lds16(vBase + vsrc[i], smem + 8192 + wave * 2048 + i * 1024);
    }

    auto astep = [&](int CUR, int NXT, int jn, int pref) {
        __syncthreads();   // tile-j loads landed; prior compute done (buffer free)
        if (pref) {
#pragma unroll
            for (int i = 0; i < 2; ++i) {
                gload_lds16(kBase + jn * 8192 + ksrc[i], smem + NXT + wave * 2048 + i * 1024);
                gload_lds16(vBase + jn * 128  + vsrc[i], smem + NXT + 8192 + wave * 2048 + i * 1024);
            }
        }

        // mask (pre-multiplied by log2e): mvl[ct][r] = maskl[key], uniform over l15
        // == exactly the C-layout broadcast -> use as QK accumulator init.
        f32x4 mvl[4];
#pragma unroll
        for (int ct = 0; ct < 4; ++ct)
            mvl[ct] = *(const f32x4*)(mSrc + ct * 64);
        mSrc += 256;

        // S^T = K * Q^T + mask : s[ct] holds C[kcol=ct*16+quad*4+r][qrow=l15]
        f32x4 s[4];
#pragma unroll
        for (int ct = 0; ct < 4; ++ct) {
            bfrag kf0 = *(const bfrag*)(smem + CUR + kAddr[0] + ct * 2048);
            bfrag kf1 = *(const bfrag*)(smem + CUR + kAddr[1] + ct * 2048);
            s[ct] = __builtin_amdgcn_mfma_f32_16x16x32_bf16(kf0, qf[0], mvl[ct], 0, 0, 0);
            s[ct] = __builtin_amdgcn_mfma_f32_16x16x32_bf16(kf1, qf[1], s[ct],   0, 0, 0);
        }

        // softmax numerators: 16 exp + 8 pack per iter, nothing else
        bfrag4 pf[4];
#pragma unroll
        for (int ct = 0; ct < 4; ++ct) {
            float e0 = __builtin_amdgcn_exp2f(s[ct][0]);
            float e1 = __builtin_amdgcn_exp2f(s[ct][1]);
            float e2 = __builtin_amdgcn_exp2f(s[ct][2]);
            float e3 = __builtin_amdgcn_exp2f(s[ct][3]);
            union { uint32_t u[2]; bfrag4 v; } cvt;
            cvt.u[0] = pack_bf16(e0, e1);
            cvt.u[1] = pack_bf16(e2, e3);
            pf[ct] = cvt.v;
        }

        // O += P*V ; l += P*ones
#pragma unroll
        for (int dt = 0; dt < 4; ++dt) {
#pragma unroll
            for (int ct = 0; ct < 4; ++ct) {
                bfrag4 vf = *(const bfrag4*)(smem + CUR + vAddr[ct] + dt * 2048);
                oacc[dt] = __builtin_amdgcn_mfma_f32_16x16x16bf16_1k(pf[ct], vf, oacc[dt], 0, 0, 0);
            }
        }
#pragma unroll
        for (int ct = 0; ct < 4; ++ct)
            ol = __builtin_amdgcn_mfma_f32_16x16x16bf16_1k(pf[ct], ones, ol, 0, 0, 0);
    };

    for (int jj = 0; jj < 16; ++jj) {
        astep(0,     16384, 2 * jj + 1, 1);
        astep(16384, 0,     2 * jj + 2, jj < 15);
    }

    // epilogue: out[b][qrow][h*64+d] fp32; O rows = quad*4+r, cols = l15 (+16*dt)
#pragma unroll
    for (int r = 0; r < 4; ++r) {
        float linv = 1.0f / ol[r];
        int qrow = qBase + quad * 4 + r;
#pragma unroll
        for (int dt = 0; dt < 4; ++dt)
            out[((size_t)(b * SS + qrow)) * HH + h * 64 + dt * 16 + l15] =
                oacc[dt][r] * linv;
    }
}

extern "C" void kernel_launch(void* const* d_in, const int* in_sizes, int n_in,
                              void* d_out, int out_size, void* d_ws, size_t ws_size,
                              hipStream_t stream) {
    const float* hs   = (const float*)d_in[0];
    const float* mask = (const float*)d_in[1];
    const float* Wq   = (const float*)d_in[2];
    const float* bq   = (const float*)d_in[3];
    const float* Wk   = (const float*)d_in[4];
    const float* bk   = (const float*)d_in[5];
    const float* Wv   = (const float*)d_in[6];
    const float* bv   = (const float*)d_in[7];
    float* out = (float*)d_out;

    char* ws = (char*)d_ws;
    short* Xb    = (short*)(ws);                      // [4096][1024] bf16, 8 MiB
    short* Wcat  = (short*)(ws + (8ull  << 20));      // [3072][1024] bf16, 6 MiB (Wq|Wk|Wv)
    short* Qb    = (short*)(ws + (14ull << 20));      // [bh][s][d] 8 MiB (pre-scaled)
    short* Kb    = (short*)(ws + (22ull << 20));      // [bh][s][d] 8 MiB
    short* Vb    = (short*)(ws + (30ull << 20));      // [bh][d][s] 8 MiB
    float* maskl = (float*)(ws + (38ull << 20));      // [B][S] fp32, 16 KiB

    cvt_all<<<7172, 256, 0, stream>>>(hs, Wq, Wk, Wv, mask, Xb, Wcat, maskl);

    qkv_gemm<<<dim3(24, 32), 256, 0, stream>>>(Xb, Wcat, bq, bk, bv, Qb, Kb, Vb);

    attn_kernel<<<dim3(SS / 64, BB * NH), 256, 0, stream>>>(Qb, Kb, Vb, maskl, out);
}

// Round 11
// 168.514 us; speedup vs baseline: 1.0424x; 1.0334x over previous
//
#include <hip/hip_runtime.h>
#include <stdint.h>

// Problem constants
#define BB 2
#define SS 2048
#define HH 1024
#define NH 16
#define HD 64

#define LOG2E 1.4426950408889634f
#define QSCALE (0.125f * LOG2E)   // folded into Q at GEMM epilogue

typedef short bfrag  __attribute__((ext_vector_type(8)));   // 8 x bf16 (4 VGPRs)
typedef short bfrag4 __attribute__((ext_vector_type(4)));   // 4 x bf16 (2 VGPRs)
typedef float f32x4  __attribute__((ext_vector_type(4)));

__device__ __forceinline__ short f2bf(float f) {
    union { float f; uint32_t u; } v; v.f = f;
    uint32_t r = (v.u + 0x7fffu + ((v.u >> 16) & 1u)) >> 16;
    return (short)r;
}

// pack two f32 -> one dword of bf16 (lo = a, hi = b)
__device__ __forceinline__ uint32_t pack_bf16(float a, float b) {
#if __has_builtin(__builtin_amdgcn_cvt_pk_bf16_f32)
    auto t = __builtin_amdgcn_cvt_pk_bf16_f32(a, b);   // RNE, single VALU op
    uint32_t u; __builtin_memcpy(&u, &t, 4);
    return u;
#else
    uint32_t ua = __float_as_uint(a) + 0x8000u;
    uint32_t ub = __float_as_uint(b) + 0x8000u;
    return __builtin_amdgcn_perm(ub, ua, 0x07060302u);
#endif
}

// fused fp32->bf16 conversion: hidden (1048576 f4) + Wq/Wk/Wv (262144 f4 each,
// into contiguous Wcat) + mask*LOG2E (1024 f4, fp32 out). grid 7172.
__global__ __launch_bounds__(256) void cvt_all(
    const float* __restrict__ X,  const float* __restrict__ Wq,
    const float* __restrict__ Wk, const float* __restrict__ Wv,
    const float* __restrict__ mask,
    short* __restrict__ Xb, short* __restrict__ Wcat,
    float* __restrict__ maskl)
{
    int i = blockIdx.x * 256 + threadIdx.x;
    if (i >= 1835008) {
        int off = i - 1835008;   // 0..1023
        float4 f = ((const float4*)mask)[off];
        f.x *= LOG2E; f.y *= LOG2E; f.z *= LOG2E; f.w *= LOG2E;
        ((float4*)maskl)[off] = f;
        return;
    }
    const float* src; short* dst; int off;
    if (i < 1048576)      { src = X;  dst = Xb;                 off = i; }
    else if (i < 1310720) { src = Wq; dst = Wcat;               off = i - 1048576; }
    else if (i < 1572864) { src = Wk; dst = Wcat + 1048576;     off = i - 1310720; }
    else                  { src = Wv; dst = Wcat + 2097152;     off = i - 1572864; }
    float4 f = ((const float4*)src)[off];
    short4 s;
    s.x = f2bf(f.x); s.y = f2bf(f.y); s.z = f2bf(f.z); s.w = f2bf(f.w);
    ((short4*)dst)[off] = s;
}

__device__ __forceinline__ void gload_lds16(const void* g, void* lds) {
    __builtin_amdgcn_global_load_lds(
        (__attribute__((address_space(1))) void*)(uintptr_t)g,
        (__attribute__((address_space(3))) void*)(uintptr_t)lds,
        16, 0, 0);
}

// Fused QKV GEMM (BK=64, 2-barrier K-loop — the known-good config).
// C[m][n] = sum_k X[m][k] * Wcat[n][k] + bias, M=4096 N=3072 K=1024.
// n in [0,1024) -> Q (pre-scaled by QSCALE), [1024,2048) -> K,
// [2048,3072) -> V^T [bh][d][s] with k-PERMUTED s within each 64-block:
// pos(k) = (g*4+q)*8 + h*4 + j for k = 32g+16h+4q+j, so one 16B chunk holds
// exactly the 8 values lane (quad=q) needs for the attn PV MFMA pair -> b128
// conflict-free V reads in attn (b64 V reads cost 4 extra bank-cycles each).
__global__ __launch_bounds__(256, 3) void qkv_gemm(
    const short* __restrict__ X, const short* __restrict__ Wcat,
    const float* __restrict__ bq, const float* __restrict__ bk, const float* __restrict__ bv,
    short* __restrict__ Qo, short* __restrict__ Ko, short* __restrict__ Vo)
{
    // main loop: As = smem[0..8191], Bs = smem[8192..16383] (shorts)
    // epilogue: reused as T[128][136] (17408 shorts)
    __shared__ __align__(16) short smem[17408];

    const int tid  = threadIdx.x;
    const int wave = tid >> 6, lane = tid & 63;
    const int quad = lane >> 4, l15 = lane & 15;
    const int mTile = blockIdx.y * 128;
    const int nTile = blockIdx.x * 128;
    const int z = nTile >> 10;                 // 0=Q,1=K,2=V (block-uniform)
    const int nLocT = nTile & 1023;
    const float* bias = (z == 0) ? bq : (z == 1) ? bk : bv;

    f32x4 acc[4][4];
#pragma unroll
    for (int i = 0; i < 4; ++i)
#pragma unroll
        for (int j = 0; j < 4; ++j) acc[i][j] = (f32x4)0.0f;

    const int srow  = lane >> 3;   // 0..7
    const int c_lin = lane & 7;
    const int mBase = (wave >> 1) * 64;
    const int nBase = (wave & 1) * 64;

    for (int k0 = 0; k0 < 1024; k0 += 64) {
        __syncthreads();
#pragma unroll
        for (int i = 0; i < 4; ++i) {
            int row = i * 32 + wave * 8 + srow;
            int cg  = c_lin ^ (row & 7);
            gload_lds16(X + (size_t)(mTile + row) * 1024 + k0 + cg * 8,
                        (char*)smem + i * 4096 + wave * 1024);
            gload_lds16(Wcat + (size_t)(nTile + row) * 1024 + k0 + cg * 8,
                        (char*)smem + 16384 + i * 4096 + wave * 1024);
        }
        __syncthreads();

#pragma unroll
        for (int kt = 0; kt < 2; ++kt) {
            bfrag af[4], bf[4];
#pragma unroll
            for (int t = 0; t < 4; ++t) {
                int arow = mBase + t * 16 + l15;
                int aslot = (kt * 4 + quad) ^ (arow & 7);
                af[t] = *(const bfrag*)((const char*)smem + arow * 128 + aslot * 16);
                int brow = nBase + t * 16 + l15;
                int bslot = (kt * 4 + quad) ^ (brow & 7);
                bf[t] = *(const bfrag*)((const char*)smem + 16384 + brow * 128 + bslot * 16);
            }
#pragma unroll
            for (int mt = 0; mt < 4; ++mt)
#pragma unroll
                for (int ct = 0; ct < 4; ++ct)
                    acc[mt][ct] = __builtin_amdgcn_mfma_f32_16x16x32_bf16(
                        af[mt], bf[ct], acc[mt][ct], 0, 0, 0);
        }
    }

    __syncthreads();   // main-loop LDS reads complete before T overwrite
    const int b = mTile >> 11, sBase = mTile & 2047;

    if (z == 2) {
        // T[n-local][s-local], pitch 136 -> k-permuted coalesced V^T stores
#pragma unroll
        for (int mt = 0; mt < 4; ++mt)
#pragma unroll
            for (int ct = 0; ct < 4; ++ct)
#pragma unroll
                for (int r = 0; r < 4; ++r) {
                    int nl = nBase + ct * 16 + l15;
                    int sl = mBase + mt * 16 + quad * 4 + r;
                    smem[nl * 136 + sl] = f2bf(acc[mt][ct][r] + bias[nLocT + nl]);
                }
        __syncthreads();
#pragma unroll
        for (int p = 0; p < 8; ++p) {
            int nl = p * 16 + (tid >> 4);     // d-row 0..127
            int cg = tid & 15;                // 16B chunk within 128-s tile
            int blk = cg >> 3;                // which 64-s block
            int c2  = cg & 7;                 // chunk within block: g = c2>>2, q = c2&3
            int base = blk * 64 + (c2 >> 2) * 32 + (c2 & 3) * 4;   // h=0 source
            int2 lo = *(const int2*)(smem + nl * 136 + base);       // k = ..+0..3
            int2 hi = *(const int2*)(smem + nl * 136 + base + 16);  // k = ..+16..19
            int4 v; v.x = lo.x; v.y = lo.y; v.z = hi.x; v.w = hi.y;
            int ng = nLocT + nl, hh = ng >> 6, d = ng & 63;
            *(int4*)(Vo + ((size_t)(b * 16 + hh) * 64 + d) * 2048 + sBase + cg * 8) = v;
        }
    } else {
        short* Out = (z == 0) ? Qo : Ko;
        float scale = (z == 0) ? QSCALE : 1.0f;
        // T[s-local][n-local], pitch 136 -> coalesced [bh][s][d] stores
#pragma unroll
        for (int mt = 0; mt < 4; ++mt)
#pragma unroll
            for (int ct = 0; ct < 4; ++ct)
#pragma unroll
                for (int r = 0; r < 4; ++r) {
                    int ml = mBase + mt * 16 + quad * 4 + r;
                    int nl = nBase + ct * 16 + l15;
                    smem[ml * 136 + nl] = f2bf((acc[mt][ct][r] + bias[nLocT + nl]) * scale);
                }
        __syncthreads();
#pragma unroll
        for (int p = 0; p < 8; ++p) {
            int ml = p * 16 + (tid >> 4);
            int c  = tid & 15;
            bfrag v8 = *(const bfrag*)(smem + ml * 136 + c * 8);
            int s  = sBase + ml;
            int nl = nLocT + c * 8, hh = nl >> 6, d = nl & 63;
            *(bfrag*)(Out + (((size_t)(b * 16 + hh) << 11) + s) * 64 + d) = v8;
        }
    }
}

// Flash attention (no-max softmax, log2 domain; Q pre-scaled by 0.125*log2e).
// One block = 64 Q rows of one (b,h); 4 waves x 16 rows. Grid 1024.
// Bc=64; LDS double-buffer with DMA staging, ONE barrier/iter.
// Mask folded into QK MFMA C-operand; P packed via v_cvt_pk_bf16_f32.
// V is k-permuted in global (see qkv) -> V reads are b128 with the same
// conflict-free bank pattern as K; each read feeds the MFMA pair (2g, 2g+1).
__global__ __launch_bounds__(256, 4) void attn_kernel(
    const short* __restrict__ Qb, const short* __restrict__ Kb, const short* __restrict__ Vb,
    const float* __restrict__ maskl, float* __restrict__ out)
{
    __shared__ __align__(16) char smem[32768];
    // stage = 16384 B: K tile [64][64] bf16 @+0 (128B rows, XOR-swizzled 16B chunks),
    //                  V^T tile [64 d][64 k-permuted] bf16 @+8192 (same layout)

    const int tid  = threadIdx.x;
    const int wave = tid >> 6, lane = tid & 63;
    const int quad = lane >> 4, l15 = lane & 15;
    const int bh = blockIdx.y, b = bh >> 4, h = bh & 15;
    const int qBase = blockIdx.x * 64 + wave * 16;

    // staging source byte offsets (wave handles chunks wave*128 + i*64 + lane)
    int ksrc[2], vsrc[2];
#pragma unroll
    for (int i = 0; i < 2; ++i) {
        int ci = wave * 128 + i * 64 + lane;
        int r = ci >> 3, c = ci & 7;
        int cs = (c ^ (r & 7)) * 16;
        ksrc[i] = r * 128  + cs;    // K source: row stride 64 shorts = 128B
        vsrc[i] = r * 4096 + cs;    // V^T source: row stride 2048 shorts = 4096B
    }
    const char* kBase = (const char*)(Kb + (size_t)bh * SS * HD);
    const char* vBase = (const char*)(Vb + (size_t)bh * HD * SS);
    const char* mSrc  = (const char*)(maskl + b * SS) + quad * 16;

    // Q fragment (MFMA B-operand): Q[qrow=l15][k=quad*8+j], pre-scaled
    const short* Qp = Qb + ((size_t)bh * SS + qBase) * HD;
    bfrag qf[2];
#pragma unroll
    for (int kt = 0; kt < 2; ++kt)
        qf[kt] = *(const bfrag*)(Qp + (size_t)l15 * HD + kt * 32 + quad * 8);

    // j-invariant LDS read offsets (within a stage)
    int kAddr[2];
#pragma unroll
    for (int kt = 0; kt < 2; ++kt)
        kAddr[kt] = l15 * 128 + (((kt * 4 + quad) ^ (l15 & 7)) * 16);
    int vAddr[2];
#pragma unroll
    for (int g = 0; g < 2; ++g)
        vAddr[g] = 8192 + l15 * 128 + (((g * 4 + quad) ^ (l15 & 7)) * 16);

    const f32x4 z4 = (f32x4)0.0f;
    const bfrag4 ones = {0x3F80, 0x3F80, 0x3F80, 0x3F80};  // bf16 1.0 x4

    f32x4 oacc[4], ol = z4;
#pragma unroll
    for (int dt = 0; dt < 4; ++dt) oacc[dt] = z4;

    // prologue: stage tile 0 into buffer 0
#pragma unroll
    for (int i = 0; i < 2; ++i) {
        gload_lds16(kBase + ksrc[i], smem + wave * 2048 + i * 1024);
        gload_lds16(vBase + vsrc[i], smem + 8192 + wave * 2048 + i * 1024);
    }

    auto astep = [&](int CUR, int NXT, int jn, int pref) {
        __syncthreads();   // tile-j loads landed; prior compute done (buffer free)
        if (pref) {
#pragma unroll
            for (int i = 0; i < 2; ++i) {
                gload_lds16(kBase + jn * 8192 + ksrc[i], smem + NXT + wave * 2048 + i * 1024);
                gload_lds16(vBase + jn * 128  + vsrc[i], smem + NXT + 8192 + wave * 2048 + i * 1024);
            }
        }

        // mask (pre-multiplied by log2e) == C-layout broadcast -> QK acc init
        f32x4 mvl[4];
#pragma unroll
        for (int ct = 0; ct < 4; ++ct)
            mvl[ct] = *(const f32x4*)(mSrc + ct * 64);
        mSrc += 256;

        // S^T = K * Q^T + mask : s[ct] holds C[kcol=ct*16+quad*4+r][qrow=l15]
        f32x4 s[4];
#pragma unroll
        for (int ct = 0; ct < 4; ++ct) {
            bfrag kf0 = *(const bfrag*)(smem + CUR + kAddr[0] + ct * 2048);
            bfrag kf1 = *(const bfrag*)(smem + CUR + kAddr[1] + ct * 2048);
            s[ct] = __builtin_amdgcn_mfma_f32_16x16x32_bf16(kf0, qf[0], mvl[ct], 0, 0, 0);
            s[ct] = __builtin_amdgcn_mfma_f32_16x16x32_bf16(kf1, qf[1], s[ct],   0, 0, 0);
        }

        // softmax numerators: 16 exp + 8 pack per iter
        bfrag4 pf[4];
#pragma unroll
        for (int ct = 0; ct < 4; ++ct) {
            float e0 = __builtin_amdgcn_exp2f(s[ct][0]);
            float e1 = __builtin_amdgcn_exp2f(s[ct][1]);
            float e2 = __builtin_amdgcn_exp2f(s[ct][2]);
            float e3 = __builtin_amdgcn_exp2f(s[ct][3]);
            union { uint32_t u[2]; bfrag4 v; } cvt;
            cvt.u[0] = pack_bf16(e0, e1);
            cvt.u[1] = pack_bf16(e2, e3);
            pf[ct] = cvt.v;
        }

        // O += P*V : one b128 V read feeds the (2g, 2g+1) MFMA pair ; l += P*ones
#pragma unroll
        for (int dt = 0; dt < 4; ++dt) {
#pragma unroll
            for (int g = 0; g < 2; ++g) {
                bfrag v = *(const bfrag*)(smem + CUR + vAddr[g] + dt * 2048);
                bfrag4 vlo = __builtin_shufflevector(v, v, 0, 1, 2, 3);
                bfrag4 vhi = __builtin_shufflevector(v, v, 4, 5, 6, 7);
                oacc[dt] = __builtin_amdgcn_mfma_f32_16x16x16bf16_1k(pf[2 * g],     vlo, oacc[dt], 0, 0, 0);
                oacc[dt] = __builtin_amdgcn_mfma_f32_16x16x16bf16_1k(pf[2 * g + 1], vhi, oacc[dt], 0, 0, 0);
            }
        }
#pragma unroll
        for (int ct = 0; ct < 4; ++ct)
            ol = __builtin_amdgcn_mfma_f32_16x16x16bf16_1k(pf[ct], ones, ol, 0, 0, 0);
    };

    for (int jj = 0; jj < 16; ++jj) {
        astep(0,     16384, 2 * jj + 1, 1);
        astep(16384, 0,     2 * jj + 2, jj < 15);
    }

    // epilogue: out[b][qrow][h*64+d] fp32; O rows = quad*4+r, cols = l15 (+16*dt)
#pragma unroll
    for (int r = 0; r < 4; ++r) {
        float linv = 1.0f / ol[r];
        int qrow = qBase + quad * 4 + r;
#pragma unroll
        for (int dt = 0; dt < 4; ++dt)
            out[((size_t)(b * SS + qrow)) * HH + h * 64 + dt * 16 + l15] =
                oacc[dt][r] * linv;
    }
}

extern "C" void kernel_launch(void* const* d_in, const int* in_sizes, int n_in,
                              void* d_out, int out_size, void* d_ws, size_t ws_size,
                              hipStream_t stream) {
    const float* hs   = (const float*)d_in[0];
    const float* mask = (const float*)d_in[1];
    const float* Wq   = (const float*)d_in[2];
    const float* bq   = (const float*)d_in[3];
    const float* Wk   = (const float*)d_in[4];
    const float* bk   = (const float*)d_in[5];
    const float* Wv   = (const float*)d_in[6];
    const float* bv   = (const float*)d_in[7];
    float* out = (float*)d_out;

    char* ws = (char*)d_ws;
    short* Xb    = (short*)(ws);                      // [4096][1024] bf16, 8 MiB
    short* Wcat  = (short*)(ws + (8ull  << 20));      // [3072][1024] bf16, 6 MiB (Wq|Wk|Wv)
    short* Qb    = (short*)(ws + (14ull << 20));      // [bh][s][d] 8 MiB (pre-scaled)
    short* Kb    = (short*)(ws + (22ull << 20));      // [bh][s][d] 8 MiB
    short* Vb    = (short*)(ws + (30ull << 20));      // [bh][d][s-permuted] 8 MiB
    float* maskl = (float*)(ws + (38ull << 20));      // [B][S] fp32, 16 KiB

    cvt_all<<<7172, 256, 0, stream>>>(hs, Wq, Wk, Wv, mask, Xb, Wcat, maskl);

    qkv_gemm<<<dim3(24, 32), 256, 0, stream>>>(Xb, Wcat, bq, bk, bv, Qb, Kb, Vb);

    attn_kernel<<<dim3(SS / 64, BB * NH), 256, 0, stream>>>(Qb, Kb, Vb, maskl, out);
}